// Round 4
// baseline (939.349 us; speedup 1.0000x reference)
//
#include <hip/hip_runtime.h>
#include <math.h>

// Problem constants
#define BB 16
#define CC 512
#define LL 8192
#define HH 32          // CC / 16
#define BC (BB * CC)
#define NTHR 256

typedef float fv4 __attribute__((ext_vector_type(4)));

// ---------------------------------------------------------------------------
// Single cooperative kernel, software-pipelined across batches.
// 512 blocks, block j owns row j of every batch.
// Stage st (0..16):
//   Phase A (st<16):  mean of x[st, j, :]  -> s[st*CC+j], bump done[st]
//   Phase B (st>=1):  wait done[st-1]==512; gates for batch st-1;
//                     scale row (st-1, j) re-reading x (L3-fresh, ~32 MiB
//                     reuse distance) and nt-storing out.
// ---------------------------------------------------------------------------
__global__ __launch_bounds__(NTHR) void k_se_pipelined(
        const float* __restrict__ x,
        const float* __restrict__ w1, const float* __restrict__ b1,
        const float* __restrict__ w2, const float* __restrict__ b2,
        float* __restrict__ out,
        float* __restrict__ s,            // BC floats
        unsigned int* __restrict__ done)  // BB counters, zeroed per call
{
    const int j   = blockIdx.x;   // 0..511  row within batch
    const int tid = threadIdx.x;  // 0..255

    __shared__ float red[NTHR / 64];
    __shared__ float sh_s[CC];
    __shared__ float part[HH][9];   // +1 pad
    __shared__ float sh_h[HH];
    __shared__ float sh_gate;

    for (int st = 0; st <= BB; ++st) {
        // ---------------- Phase A: mean of row (st, j) ----------------
        if (st < BB) {
            const fv4* xr = (const fv4*)(x + ((size_t)st * CC + j) * LL);
            float acc = 0.0f;
#pragma unroll
            for (int i = 0; i < LL / 4 / NTHR; ++i) {      // 8 iters
                fv4 v = xr[i * NTHR + tid];
                acc += (v.x + v.y) + (v.z + v.w);
            }
#pragma unroll
            for (int off = 32; off > 0; off >>= 1)
                acc += __shfl_down(acc, off, 64);
            if ((tid & 63) == 0) red[tid >> 6] = acc;
            __syncthreads();
            if (tid == 0) {
                float t = (red[0] + red[1]) + (red[2] + red[3]);
                __hip_atomic_store(&s[st * CC + j], t * (1.0f / (float)LL),
                                   __ATOMIC_RELEASE, __HIP_MEMORY_SCOPE_AGENT);
                __hip_atomic_fetch_add(&done[st], 1u,
                                   __ATOMIC_RELEASE, __HIP_MEMORY_SCOPE_AGENT);
            }
        }

        // ------------- Phase B+C: gates + scale for batch st-1 -------------
        if (st >= 1) {
            const int pb = st - 1;
            if (tid == 0) {
                while (__hip_atomic_load(&done[pb], __ATOMIC_ACQUIRE,
                                         __HIP_MEMORY_SCOPE_AGENT) < (unsigned)CC) {
                    __builtin_amdgcn_s_sleep(2);
                }
            }
            __syncthreads();

            // stage s[pb,:] in LDS (agent-scope loads: cross-XCD safe)
            sh_s[tid] = __hip_atomic_load(&s[pb * CC + tid],
                            __ATOMIC_RELAXED, __HIP_MEMORY_SCOPE_AGENT);
            sh_s[tid + 256] = __hip_atomic_load(&s[pb * CC + tid + 256],
                            __ATOMIC_RELAXED, __HIP_MEMORY_SCOPE_AGENT);
            __syncthreads();

            // h[hj] = relu(b1[hj] + sum_c sh_s[c] * w1[hj,c])
            {
                const int hj  = tid >> 3;   // 0..31
                const int seg = tid & 7;    // 0..7, 64 c's each
                const float* wrow = w1 + (size_t)hj * CC + seg * 64;
                const float* srow = sh_s + seg * 64;
                float p = 0.0f;
#pragma unroll
                for (int c = 0; c < 64; ++c) p += srow[c] * wrow[c];
                part[hj][seg] = p;
            }
            __syncthreads();
            if (tid < HH) {
                float t = b1[tid];
#pragma unroll
                for (int k = 0; k < 8; ++k) t += part[tid][k];
                sh_h[tid] = t > 0.0f ? t : 0.0f;
            }
            __syncthreads();
            if (tid == 0) {
                const float* wrow = w2 + (size_t)j * HH;
                float z = b2[j];
#pragma unroll
                for (int k = 0; k < HH; ++k) z += sh_h[k] * wrow[k];
                sh_gate = 1.0f / (1.0f + expf(-z));
            }
            __syncthreads();

            const float gate = sh_gate;
            const size_t off = ((size_t)pb * CC + j) * (size_t)LL;
            const fv4* xr  = (const fv4*)(x + off);
            fv4*       orr = (fv4*)(out + off);
#pragma unroll
            for (int i = 0; i < LL / 4 / NTHR; ++i) {
                fv4 v = xr[i * NTHR + tid];
                v *= gate;
                __builtin_nontemporal_store(v, &orr[i * NTHR + tid]);
            }
            __syncthreads();   // protect LDS reuse next stage
        } else {
            __syncthreads();   // st==0: protect red[] reuse
        }
    }
}

extern "C" void kernel_launch(void* const* d_in, const int* in_sizes, int n_in,
                              void* d_out, int out_size, void* d_ws, size_t ws_size,
                              hipStream_t stream) {
    const float* x  = (const float*)d_in[0];
    const float* w1 = (const float*)d_in[1];
    const float* b1 = (const float*)d_in[2];
    const float* w2 = (const float*)d_in[3];
    const float* b2 = (const float*)d_in[4];
    float* out = (float*)d_out;

    float* s = (float*)d_ws;                       // BC floats
    unsigned int* done = (unsigned int*)(s + BC);  // BB counters

    // deterministic per-call counter reset (graph-capturable)
    hipMemsetAsync(done, 0, BB * sizeof(unsigned int), stream);

    void* args[] = {(void*)&x, (void*)&w1, (void*)&b1, (void*)&w2,
                    (void*)&b2, (void*)&out, (void*)&s, (void*)&done};
    hipLaunchCooperativeKernel((const void*)k_se_pipelined,
                               dim3(CC), dim3(NTHR), args, 0, stream);
}

// Round 5
// 156.201 us; speedup vs baseline: 6.0137x; 6.0137x over previous
//
#include <hip/hip_runtime.h>
#include <math.h>

// Problem constants
#define BB 16
#define CC 512
#define LL 8192
#define HH 32            // CC / 16
#define BC (BB * CC)
#define CHUNKB 4         // batches per chunk (64 MiB of x)

typedef float fv4 __attribute__((ext_vector_type(4)));

// ---------------------------------------------------------------------------
// Mean over L for one chunk of batches.  One block per row, 256 threads,
// 8 float4 per thread.  Cached loads on purpose: x must land in L3 so the
// scale pass (same chunk, 64 MiB reuse distance) re-reads it from L3.
// ---------------------------------------------------------------------------
__global__ __launch_bounds__(256) void k_mean(const float* __restrict__ x,
                                              float* __restrict__ s,
                                              int rowBase) {
    const int row = rowBase + blockIdx.x;
    const int tid = threadIdx.x;
    const fv4* xr = (const fv4*)(x + (size_t)row * LL);

    float acc = 0.0f;
#pragma unroll
    for (int i = 0; i < LL / 4 / 256; ++i) {          // 8 iterations
        fv4 v = xr[i * 256 + tid];
        acc += (v.x + v.y) + (v.z + v.w);
    }
#pragma unroll
    for (int off = 32; off > 0; off >>= 1)
        acc += __shfl_down(acc, off, 64);

    __shared__ float part[4];
    if ((tid & 63) == 0) part[tid >> 6] = acc;
    __syncthreads();
    if (tid == 0) {
        float t = (part[0] + part[1]) + (part[2] + part[3]);
        s[row] = t * (1.0f / (float)LL);
    }
}

// ---------------------------------------------------------------------------
// Fused gates + scale for one chunk.  Each block: 4 channels of one batch.
// Redundant per-block h-compute (w1 is 64 KiB, L2-resident — cheap), then
// scale 4 rows with nt-stores (keep out stream from evicting x in L3).
// ---------------------------------------------------------------------------
__global__ __launch_bounds__(256) void k_scale_fused(
        const float* __restrict__ x,  const float* __restrict__ s,
        const float* __restrict__ w1, const float* __restrict__ b1,
        const float* __restrict__ w2, const float* __restrict__ b2,
        float* __restrict__ out, int batchBase) {
    const int bid   = blockIdx.x;          // 0..CHUNKB*128-1
    const int b     = batchBase + (bid >> 7);
    const int chunk = bid & 127;           // 4 channels each
    const int tid   = threadIdx.x;

    __shared__ float partial[HH][9];       // +1 pad
    __shared__ float h[HH];
    __shared__ float g4[4];

    // h[j] = relu(b1[j] + sum_c s[b,c] * w1[j,c])
    {
        const int j   = tid >> 3;          // 0..31
        const int seg = tid & 7;           // 0..7, 64 c's each
        const float* srow = s  + b * CC + seg * 64;
        const float* wrow = w1 + (size_t)j * CC + seg * 64;
        float p = 0.0f;
#pragma unroll
        for (int c = 0; c < 64; ++c) p += srow[c] * wrow[c];
        partial[j][seg] = p;
    }
    __syncthreads();
    if (tid < HH) {
        float t = b1[tid];
#pragma unroll
        for (int k = 0; k < 8; ++k) t += partial[tid][k];
        h[tid] = t > 0.0f ? t : 0.0f;
    }
    __syncthreads();
    if (tid < 4) {
        const int c = chunk * 4 + tid;
        const float* wrow = w2 + (size_t)c * HH;
        float z = b2[c];
#pragma unroll
        for (int j = 0; j < HH; ++j) z += h[j] * wrow[j];
        g4[tid] = 1.0f / (1.0f + expf(-z));
    }
    __syncthreads();

#pragma unroll
    for (int r = 0; r < 4; ++r) {
        const int c = chunk * 4 + r;
        const size_t off = ((size_t)b * CC + c) * (size_t)LL;
        const fv4* xr  = (const fv4*)(x + off);
        fv4*       orr = (fv4*)(out + off);
        const float gate = g4[r];
#pragma unroll
        for (int i = 0; i < LL / 4 / 256; ++i) {
            fv4 v = xr[i * 256 + tid];
            v *= gate;
            __builtin_nontemporal_store(v, &orr[i * 256 + tid]);
        }
    }
}

extern "C" void kernel_launch(void* const* d_in, const int* in_sizes, int n_in,
                              void* d_out, int out_size, void* d_ws, size_t ws_size,
                              hipStream_t stream) {
    const float* x  = (const float*)d_in[0];
    const float* w1 = (const float*)d_in[1];
    const float* b1 = (const float*)d_in[2];
    const float* w2 = (const float*)d_in[3];
    const float* b2 = (const float*)d_in[4];
    float* out = (float*)d_out;

    float* s = (float*)d_ws;               // BC floats

    for (int c0 = 0; c0 < BB; c0 += CHUNKB) {
        k_mean       <<<CHUNKB * CC,     256, 0, stream>>>(x, s, c0 * CC);
        k_scale_fused<<<CHUNKB * CC / 4, 256, 0, stream>>>(x, s, w1, b1, w2,
                                                           b2, out, c0);
    }
}